// Round 12
// baseline (2883.501 us; speedup 1.0000x reference)
//
#include <hip/hip_runtime.h>

#define N_NODES 2048
#define KSEL 50

typedef float v2f __attribute__((ext_vector_type(2)));

// ---- order-preserving fp32 <-> uint map (monotone: bigger float => bigger uint)
__device__ __forceinline__ unsigned ford(float f) {
  unsigned b = __float_as_uint(f);
  return b ^ ((b & 0x80000000u) ? 0xFFFFFFFFu : 0x80000000u);
}
__device__ __forceinline__ float funord(unsigned u) {
  unsigned b = (u & 0x80000000u) ? (u ^ 0x80000000u) : ~u;
  return __uint_as_float(b);
}

// 1-sub-counter hist layout: bin b -> word ((b&63)<<2)|(b>>6).
// Scan: lane reads uint4 at [lane*4] = bins {g*64+lane}, g=0..3 (components).
__device__ __forceinline__ int hidx1(unsigned b) {
  return (int)(((b & 63u) << 2) | (b >> 6));
}

// shared single-layer MLP tile: acc[16] = relu(bias + xs^T W), xs transposed layout
__device__ __forceinline__ void mlp_layer(float acc[16], const float* xs,
                                          const float* Ws, const float* bs,
                                          int r, int cg) {
  const float4* Ws4 = (const float4*)Ws;
#pragma unroll
  for (int i = 0; i < 16; ++i) acc[i] = bs[cg * 16 + i];
#pragma unroll 8
  for (int k = 0; k < 64; ++k) {
    float xv = xs[k * 65 + r];
    float4 w0 = Ws4[k * 16 + cg * 4 + 0];
    float4 w1 = Ws4[k * 16 + cg * 4 + 1];
    float4 w2 = Ws4[k * 16 + cg * 4 + 2];
    float4 w3 = Ws4[k * 16 + cg * 4 + 3];
    acc[0]  += xv * w0.x; acc[1]  += xv * w0.y; acc[2]  += xv * w0.z; acc[3]  += xv * w0.w;
    acc[4]  += xv * w1.x; acc[5]  += xv * w1.y; acc[6]  += xv * w1.z; acc[7]  += xv * w1.w;
    acc[8]  += xv * w2.x; acc[9]  += xv * w2.y; acc[10] += xv * w2.z; acc[11] += xv * w2.w;
    acc[12] += xv * w3.x; acc[13] += xv * w3.y; acc[14] += xv * w3.z; acc[15] += xv * w3.w;
  }
#pragma unroll
  for (int i = 0; i < 16; ++i) acc[i] = fmaxf(acc[i], 0.f);
}

// Fused embedding: h1=relu(x@w0+b0); h2=relu(h1@w1+b1) -> A, AT; msg0=relu(h2@wm+bm) -> M
__global__ __launch_bounds__(256) void emb3_kernel(
    const float* __restrict__ x,
    const float* __restrict__ ew0, const float* __restrict__ eb0,
    const float* __restrict__ ew1, const float* __restrict__ eb1,
    const float* __restrict__ wmm, const float* __restrict__ bmm,
    float* __restrict__ outA, float* __restrict__ outAT, float* __restrict__ outM)
{
  const int tid = threadIdx.x;
  const int r = tid & 63, cg = tid >> 6;
  const size_t rowbase = (size_t)blockIdx.x * 64;
  __shared__ float xs[64 * 65];
  __shared__ float Ws[64 * 64];
  __shared__ float bs[64];
  float acc[16];

#pragma unroll
  for (int i = 0; i < 16; ++i) {
    int idx = tid + 256 * i;
    xs[(idx & 63) * 65 + (idx >> 6)] = x[rowbase * 64 + idx];
    Ws[idx] = ew0[idx];
  }
  if (tid < 64) bs[tid] = eb0[tid];
  __syncthreads();
  mlp_layer(acc, xs, Ws, bs, r, cg);             // h1
  __syncthreads();
#pragma unroll
  for (int i = 0; i < 16; ++i) {
    xs[(cg * 16 + i) * 65 + r] = acc[i];
    Ws[tid + 256 * i] = ew1[tid + 256 * i];
  }
  if (tid < 64) bs[tid] = eb1[tid];
  __syncthreads();
  mlp_layer(acc, xs, Ws, bs, r, cg);             // h2
  {
    float4* o4 = (float4*)(outA + (rowbase + r) * 64 + cg * 16);
#pragma unroll
    for (int q = 0; q < 4; ++q)
      o4[q] = make_float4(acc[q*4+0], acc[q*4+1], acc[q*4+2], acc[q*4+3]);
  }
  __syncthreads();
#pragma unroll
  for (int i = 0; i < 16; ++i) {
    xs[(cg * 16 + i) * 65 + r] = acc[i];
    Ws[tid + 256 * i] = wmm[tid + 256 * i];
  }
  if (tid < 64) bs[tid] = bmm[tid];
  __syncthreads();
  {   // flush AT (h2 transposed, feature-major)
    const size_t bb = rowbase >> 11;
    const int nbase = (int)(rowbase & 2047);
    const int c = tid >> 2, seg = tid & 3;
    float* oT = outAT + bb * 64 * N_NODES + (size_t)c * N_NODES + nbase + seg * 16;
#pragma unroll
    for (int q = 0; q < 4; ++q)
      ((float4*)oT)[q] = make_float4(xs[c*65+seg*16+q*4+0], xs[c*65+seg*16+q*4+1],
                                     xs[c*65+seg*16+q*4+2], xs[c*65+seg*16+q*4+3]);
  }
  mlp_layer(acc, xs, Ws, bs, r, cg);             // msg0
  {
    float4* o4 = (float4*)(outM + (rowbase + r) * 64 + cg * 16);
#pragma unroll
    for (int q = 0; q < 4; ++q)
      o4[q] = make_float4(acc[q*4+0], acc[q*4+1], acc[q*4+2], acc[q*4+3]);
  }
}

// Fused mp: S = h_tile . h^T in LDS (Sbuf, raw FLOATS — S >= 0 so float compare
// == ordered-uint compare; ford only on gated radix candidates), 512 thr,
// ~78 KB LDS -> 2 blocks/CU. Wave-private top-50. Select re-reads Srow from LDS
// (reg-array across select loop spills at the 128-reg cap — R9 evidence).
// FINAL output is fused into the extraction pass; ties fixed by scattered
// stores after tie-resolve.
template <bool FINAL, bool MSG>
__global__ __launch_bounds__(512, 4) void mp_kernel(
    const float* __restrict__ h, const float* __restrict__ hT,
    const float* __restrict__ msg,
    const float* __restrict__ wu, const float* __restrict__ bu,
    const float* __restrict__ wm, const float* __restrict__ bm,
    float* __restrict__ outp, float* __restrict__ outT, float* __restrict__ outM)
{
  const int tid = threadIdx.x;
  const int lane = tid & 63;
  const int w64 = tid >> 6;               // 8 waves <-> 8 rows
  const int bid = blockIdx.x;
  const int b = bid & 7;                  // round-robin blockIdx->XCD: 1 batch/XCD
  const int n0 = (bid >> 3) * 8;

  __shared__ float Sbuf[8 * N_NODES];     // 64 KB float S tile (+overlays)
  __shared__ unsigned hist[8][256];       // per-wave radix histograms (8 KB)
  __shared__ float hrL[8 * 64];           // MP epilogue row tile
  __shared__ float LwMin[8][8], LwMax[8][8];   // [wave][row] prefilter staging
  __shared__ int   seli[8][52];
  __shared__ float selv[8][52];
  __shared__ int   eqlist[8][64];

  const float* hb  = h  + (size_t)b * N_NODES * 64;
  const float* hTb = hT + (size_t)b * 64 * N_NODES;
  const float* colp = hTb + 4 * tid;      // 512 threads x 4 cols = 2048

  // prefetch ring depth 4 (issued before anything else)
  float4 pf[4];
#pragma unroll
  for (int i = 0; i < 4; ++i) pf[i] = *(const float4*)(colp + (size_t)i * 2048);

  if (!FINAL) hrL[tid] = hb[(size_t)n0 * 64 + tid];
  for (int i = tid; i < 8 * 256; i += 512) (&hist[0][0])[i] = 0;

  // ---- FMA phase: acc2[r*2+(e>>1)][e&1] = S[r][4*tid+e]; rows via s_load
  v2f acc2[16];
#pragma unroll
  for (int i = 0; i < 16; ++i) { acc2[i][0] = 0.f; acc2[i][1] = 0.f; }

  const float* hrow = hb + (size_t)n0 * 64;        // block-uniform -> SGPR loads
  for (int k4 = 0; k4 < 16; ++k4) {
    float4 a[8];
#pragma unroll
    for (int r = 0; r < 8; ++r)
      a[r] = *(const float4*)(hrow + r * 64 + k4 * 4);
#pragma unroll
    for (int kk = 0; kk < 4; ++kk) {
      const int k = k4 * 4 + kk;
      float4 cu = pf[kk];
      if (k + 4 < 64) pf[kk] = *(const float4*)(colp + (size_t)(k + 4) * 2048);
      v2f c00 = {cu.x, cu.y}, c01 = {cu.z, cu.w};
#pragma unroll
      for (int r = 0; r < 8; ++r) {
        const float ar = ((const float*)&a[r])[kk];
        v2f as = {ar, ar};
        acc2[r*2+0] = __builtin_elementwise_fma(as, c00, acc2[r*2+0]);
        acc2[r*2+1] = __builtin_elementwise_fma(as, c01, acc2[r*2+1]);
      }
    }
  }

  // ---- park raw floats in LDS + reg-based prefilter reductions (float min/max)
#pragma unroll
  for (int r = 0; r < 8; ++r) {
    float4 w = make_float4(acc2[r*2+0][0], acc2[r*2+0][1],
                           acc2[r*2+1][0], acc2[r*2+1][1]);
    *(float4*)&Sbuf[r * N_NODES + 4 * tid] = w;
    float lm = fmaxf(fmaxf(w.x, w.y), fmaxf(w.z, w.w));  // lane max of its 4
    float mn = lm, mx = lm;
#pragma unroll
    for (int off = 32; off >= 1; off >>= 1) {
      float o1 = __shfl_xor(mn, off, 64);
      float o2 = __shfl_xor(mx, off, 64);
      mn = fminf(mn, o1);                // wave-min of lane maxes
      mx = fmaxf(mx, o2);                // wave-max
    }
    if (lane == 0) { LwMin[w64][r] = mn; LwMax[w64][r] = mx; }
  }
  __syncthreads();                       // barrier 1: Sbuf/LwMM/hrL ready

  // ======== wave-private selection: wave w64 owns row rw ========
  const int rw = w64;
  const float* Srow = &Sbuf[rw * N_NODES];
  float Lvf, Tf;
  {
    float lmn = (lane < 8) ? LwMin[lane][rw] : 0.f;
    float lmx = (lane < 8) ? LwMax[lane][rw] : 0.f;
#pragma unroll
    for (int off = 4; off >= 1; off >>= 1) {
      float o1 = __shfl_xor(lmn, off, 8);
      float o2 = __shfl_xor(lmx, off, 8);
      lmn = fmaxf(lmn, o1);              // L = max over waves of wave-mins
      lmx = fmaxf(lmx, o2);              // M = row max
    }
    Lvf = __shfl(lmn, 0, 64);
    float Mvf = __shfl(lmx, 0, 64);

    if (Lvf == Mvf) {
      Tf = Mvf;                          // >=64 copies of the max
    } else {
      const unsigned Lu = ford(Lvf), Mu = ford(Mvf);
      int sh = 24 - 8 * (__builtin_clz(Lu ^ Mu) >> 3);
      unsigned pv = (sh == 24) ? 0u : (Lu >> (sh + 8));
      unsigned Kc = KSEL;
      int mode = 0;                      // 0=HIST 1=PROBE 2=DONE
      unsigned* hrw = hist[rw];
      for (int it = 0; it < 5 && mode != 2; ++it) {
        const int s = sh + 8;            // 8..32
        const unsigned lo = (s >= 32) ? 0u : (pv << s);
        const unsigned hi = (s >= 32) ? 0xFFFFFFFFu : (lo | ((1u << s) - 1u));
        if (mode == 0) {
#pragma unroll
          for (int i = 0; i < 8; ++i) {
            float4 q = *(const float4*)&Srow[i * 256 + 4 * lane];
            float qq[4] = {q.x, q.y, q.z, q.w};
#pragma unroll
            for (int e = 0; e < 4; ++e) {
              float fv = qq[e];
              if (fv >= Lvf) {           // cheap float gate first
                unsigned u = ford(fv);
                if (u >= lo && u <= hi)  // 32-bit range test (no 64-bit shifts)
                  atomicAdd(&hrw[hidx1((u >> sh) & 255u)], 1u);
              }
            }
          }
          uint4 q = *(const uint4*)&hrw[lane * 4];
          *(uint4*)&hrw[lane * 4] = make_uint4(0, 0, 0, 0);
          unsigned c0 = q.x, c1 = q.y, c2 = q.z, c3 = q.w;
          unsigned s0 = c0, s1 = c1, s2 = c2, s3 = c3;   // suffix over lanes
#pragma unroll
          for (int off = 1; off < 64; off <<= 1) {
            unsigned t0=__shfl_down((int)s0,off,64), t1=__shfl_down((int)s1,off,64);
            unsigned t2=__shfl_down((int)s2,off,64), t3=__shfl_down((int)s3,off,64);
            if (lane + off < 64) { s0+=t0; s1+=t1; s2+=t2; s3+=t3; }
          }
          unsigned T1=(unsigned)__shfl((int)s1,0,64);
          unsigned T2=(unsigned)__shfl((int)s2,0,64);
          unsigned T3=(unsigned)__shfl((int)s3,0,64);
          unsigned cA[4] = {c0, c1, c2, c3};
          unsigned AA[4] = {s0 - c0 + T1 + T2 + T3, s1 - c1 + T2 + T3,
                            s2 - c2 + T3,           s3 - c3};
          int fg = -1;
#pragma unroll
          for (int g = 0; g < 4; ++g)
            if (AA[g] < Kc && Kc <= AA[g] + cA[g]) fg = g;
          unsigned long long mk = __ballot(fg >= 0);
          int src = __ffsll(mk) - 1;     // exactly one lane fires
          unsigned bin = 0, nKc = 0, cnt = 0;
          if (fg >= 0) {
            bin = (unsigned)(fg * 64 + lane);
            nKc = Kc - AA[fg];
            cnt = cA[fg];
          }
          bin = (unsigned)__shfl((int)bin, src, 64);
          nKc = (unsigned)__shfl((int)nKc, src, 64);
          cnt = (unsigned)__shfl((int)cnt, src, 64);
          pv = (pv << 8) | bin;
          Kc = nKc;
          sh -= 8;
          if (sh < 0)        { Tf = funord(pv); mode = 2; }
          else if (cnt == 1) mode = 1;
        } else {
          // PROBE: the unique candidate in [lo,hi] is T (returned as float)
          float found = 0.f; bool has = false;
#pragma unroll
          for (int i = 0; i < 8; ++i) {
            float4 q = *(const float4*)&Srow[i * 256 + 4 * lane];
            float qq[4] = {q.x, q.y, q.z, q.w};
#pragma unroll
            for (int e = 0; e < 4; ++e) {
              float fv = qq[e];
              if (fv >= Lvf) {
                unsigned u = ford(fv);
                if (u >= lo && u <= hi) { found = fv; has = true; }
              }
            }
          }
          unsigned long long mk = __ballot(has);
          int src = __ffsll(mk) - 1;
          Tf = __shfl(found, src, 64);
          mode = 2;
        }
      }
    }
  }

  // ---- extraction (+ fused FINAL output): load row once, counts + prefix scans
  float fvals[32];
  int cgt = 0, ceq = 0;
#pragma unroll
  for (int i = 0; i < 8; ++i) {
    float4 q = *(const float4*)&Srow[i * 256 + 4 * lane];
    fvals[i*4+0] = q.x; fvals[i*4+1] = q.y; fvals[i*4+2] = q.z; fvals[i*4+3] = q.w;
#pragma unroll
    for (int e = 0; e < 4; ++e) {
      cgt += (fvals[i*4+e] > Tf);
      ceq += (fvals[i*4+e] == Tf);
    }
  }
  int sg = cgt, se = ceq;
#pragma unroll
  for (int off = 1; off < 64; off <<= 1) {
    int t0 = __shfl_up(sg, off, 64), t1 = __shfl_up(se, off, 64);
    if (lane >= off) { sg += t0; se += t1; }
  }
  const int gW = __shfl(sg, 63, 64);     // total winners (> T), < 50
  const int eTot = __shfl(se, 63, 64);
  int gb = sg - cgt, eb = se - ceq;      // exclusive bases

  float* ob = FINAL ? (outp + ((size_t)b * N_NODES + n0 + rw) * N_NODES) : nullptr;
  if constexpr (FINAL) {
    // masked dense write fused into extraction; ties fixed up after resolve
#pragma unroll
    for (int i = 0; i < 8; ++i) {
      float4 w; float* wf = (float*)&w;
#pragma unroll
      for (int e = 0; e < 4; ++e) {
        float fv = fvals[i*4+e];
        wf[e] = (fv > Tf) ? fv : 0.f;
        if (fv == Tf) { if (eb < 64) eqlist[rw][eb] = i * 256 + 4 * lane + e; ++eb; }
      }
      *(float4*)(ob + i * 256 + 4 * lane) = w;
    }
  } else {
#pragma unroll
    for (int i = 0; i < 8; ++i) {
#pragma unroll
      for (int e = 0; e < 4; ++e) {
        float fv = fvals[i*4+e];
        int m = i * 256 + 4 * lane + e;
        if (fv > Tf) { seli[rw][gb] = m; selv[rw][gb] = fv; ++gb; }
        else if (fv == Tf) { if (eb < 64) eqlist[rw][eb] = m; ++eb; }
      }
    }
  }
  const int eW = eTot < 64 ? eTot : 64;

  // ---- tie-resolve, wave-parallel: `need` smallest indices among equals
  const int needW = KSEL - gW;
  {
    int myi = (lane < eW) ? eqlist[rw][lane] : 0x7FFFFFFF;
    for (int t = 0; t < needW; ++t) {
      int mn = myi;
#pragma unroll
      for (int off = 32; off >= 1; off >>= 1) {
        int o = __shfl_xor(mn, off, 64);
        mn = mn < o ? mn : o;
      }
      if (mn == 0x7FFFFFFF) break;
      if (myi == mn) {
        seli[rw][gW + t] = mn; selv[rw][gW + t] = Tf;
        myi = 0x7FFFFFFF;
      }
    }
  }

  if constexpr (FINAL) {
    if (lane < needW) ob[seli[rw][gW + lane]] = Tf;      // tie fixups
  } else {
    // aggregation into per-row Sbuf overlay (wave-private region)
    float* aggbR = &Sbuf[rw * N_NODES + 1024];
    {
      const float* msgb = msg + (size_t)b * N_NODES * 64;
      float a = 0.f;
      for (int i = 0; i < KSEL; ++i) {
        int mi = seli[rw][i];              // wave-uniform LDS broadcast
        float vvv = selv[rw][i];
        a += vvv * msgb[(size_t)mi * 64 + lane];
      }
      aggbR[lane] = a;
    }
    // update MLP: h2[rw][lane]
    float s = bu[lane];
#pragma unroll 8
    for (int jj = 0; jj < 64; ++jj)
      s += hrL[rw * 64 + jj] * wu[jj * 64 + lane];
#pragma unroll 8
    for (int jj = 0; jj < 64; ++jj)
      s += aggbR[jj] * wu[(64 + jj) * 64 + lane];
    s = fmaxf(s, 0.f);
    outp[((size_t)b * N_NODES + n0 + rw) * 64 + lane] = s;

    if constexpr (MSG) {
      // fused next-layer message into a DISJOINT buffer (no aliasing with msg)
      float* h2row = &Sbuf[rw * N_NODES + 1152];  // wave-private overlay
      h2row[lane] = s;                   // same-wave DS ordering: no barrier
      float sm = bm[lane];
#pragma unroll 8
      for (int jj = 0; jj < 64; ++jj)
        sm += h2row[jj] * wm[jj * 64 + lane];
      outM[((size_t)b * N_NODES + n0 + rw) * 64 + lane] = fmaxf(sm, 0.f);
    }

    __syncthreads();                     // all waves done with Sbuf
    float* otF = Sbuf;                   // transpose staging overlay
    otF[lane * 9 + rw] = s;              // stride 9: conflict-free
    __syncthreads();
    {
      int f = tid >> 3, rr = tid & 7;
      outT[(size_t)b * 64 * N_NODES + (size_t)f * N_NODES + n0 + rr] = otF[f * 9 + rr];
    }
  }
}

extern "C" void kernel_launch(void* const* d_in, const int* in_sizes, int n_in,
                              void* d_out, int out_size, void* d_ws, size_t ws_size,
                              hipStream_t stream)
{
  (void)in_sizes; (void)n_in; (void)out_size; (void)ws_size;
  const float* x   = (const float*)d_in[0];
  const float* ew0 = (const float*)d_in[1];
  const float* eb0 = (const float*)d_in[2];
  const float* ew1 = (const float*)d_in[3];
  const float* eb1 = (const float*)d_in[4];
  const float* w0m = (const float*)d_in[5];
  const float* b0m = (const float*)d_in[6];
  const float* w0u = (const float*)d_in[7];
  const float* b0u = (const float*)d_in[8];
  const float* w1m = (const float*)d_in[9];
  const float* b1m = (const float*)d_in[10];
  const float* w1u = (const float*)d_in[11];
  const float* b1u = (const float*)d_in[12];
  float* out = (float*)d_out;
  float* ws = (float*)d_ws;

  const size_t BUF = (size_t)8 * N_NODES * 64;  // 4 MB each, 20 MB total ws
  float* A   = ws;
  float* AT  = ws + 1 * BUF;
  float* Bf  = ws + 2 * BUF;
  float* BfT = ws + 3 * BUF;
  float* C   = ws + 4 * BUF;
  // msg1 scratch: first 4 MB of the 128 MB output buffer. Safe: consumed by
  // mp1, then the final mp overwrites all of `out` (same-stream ordering).
  float* D   = out;

  // fused embedding (2 layers) + msg0
  emb3_kernel<<<256, 256, 0, stream>>>(x, ew0, eb0, ew1, eb1, w0m, b0m, A, AT, C);

  // MP layer 0 (consumes msg0=C, produces Bf/BfT; fused msg1 -> D, disjoint)
  mp_kernel<false, true><<<2048, 512, 0, stream>>>(
      A, AT, C, w0u, b0u, w1m, b1m, Bf, BfT, D);

  // MP layer 1 (consumes msg1=D, produces A/AT)
  mp_kernel<false, false><<<2048, 512, 0, stream>>>(
      Bf, BfT, D, w1u, b1u, nullptr, nullptr, A, AT, nullptr);

  // final dense top-k adjacency (overwrites all of out)
  mp_kernel<true, false><<<2048, 512, 0, stream>>>(
      A, AT, nullptr, nullptr, nullptr, nullptr, nullptr, out, nullptr, nullptr);
}

// Round 13
// 609.486 us; speedup vs baseline: 4.7310x; 4.7310x over previous
//
#include <hip/hip_runtime.h>

#define N_NODES 2048
#define KSEL 50

typedef float v2f __attribute__((ext_vector_type(2)));

// ---- order-preserving fp32 <-> uint map (monotone: bigger float => bigger uint)
__device__ __forceinline__ unsigned ford(float f) {
  unsigned b = __float_as_uint(f);
  return b ^ ((b & 0x80000000u) ? 0xFFFFFFFFu : 0x80000000u);
}
__device__ __forceinline__ float funord(unsigned u) {
  unsigned b = (u & 0x80000000u) ? (u ^ 0x80000000u) : ~u;
  return __uint_as_float(b);
}

// 1-sub-counter hist layout: bin b -> word ((b&63)<<2)|(b>>6).
// Scan: lane reads uint4 at [lane*4] = bins {g*64+lane}, g=0..3 (components).
__device__ __forceinline__ int hidx1(unsigned b) {
  return (int)(((b & 63u) << 2) | (b >> 6));
}

// shared single-layer MLP tile: acc[16] = relu(bias + xs^T W), xs transposed layout
__device__ __forceinline__ void mlp_layer(float acc[16], const float* xs,
                                          const float* Ws, const float* bs,
                                          int r, int cg) {
  const float4* Ws4 = (const float4*)Ws;
#pragma unroll
  for (int i = 0; i < 16; ++i) acc[i] = bs[cg * 16 + i];
#pragma unroll 8
  for (int k = 0; k < 64; ++k) {
    float xv = xs[k * 65 + r];
    float4 w0 = Ws4[k * 16 + cg * 4 + 0];
    float4 w1 = Ws4[k * 16 + cg * 4 + 1];
    float4 w2 = Ws4[k * 16 + cg * 4 + 2];
    float4 w3 = Ws4[k * 16 + cg * 4 + 3];
    acc[0]  += xv * w0.x; acc[1]  += xv * w0.y; acc[2]  += xv * w0.z; acc[3]  += xv * w0.w;
    acc[4]  += xv * w1.x; acc[5]  += xv * w1.y; acc[6]  += xv * w1.z; acc[7]  += xv * w1.w;
    acc[8]  += xv * w2.x; acc[9]  += xv * w2.y; acc[10] += xv * w2.z; acc[11] += xv * w2.w;
    acc[12] += xv * w3.x; acc[13] += xv * w3.y; acc[14] += xv * w3.z; acc[15] += xv * w3.w;
  }
#pragma unroll
  for (int i = 0; i < 16; ++i) acc[i] = fmaxf(acc[i], 0.f);
}

// Fused embedding: h1=relu(x@w0+b0); h2=relu(h1@w1+b1) -> A, AT; msg0=relu(h2@wm+bm) -> M
__global__ __launch_bounds__(256) void emb3_kernel(
    const float* __restrict__ x,
    const float* __restrict__ ew0, const float* __restrict__ eb0,
    const float* __restrict__ ew1, const float* __restrict__ eb1,
    const float* __restrict__ wmm, const float* __restrict__ bmm,
    float* __restrict__ outA, float* __restrict__ outAT, float* __restrict__ outM)
{
  const int tid = threadIdx.x;
  const int r = tid & 63, cg = tid >> 6;
  const size_t rowbase = (size_t)blockIdx.x * 64;
  __shared__ float xs[64 * 65];
  __shared__ float Ws[64 * 64];
  __shared__ float bs[64];
  float acc[16];

#pragma unroll
  for (int i = 0; i < 16; ++i) {
    int idx = tid + 256 * i;
    xs[(idx & 63) * 65 + (idx >> 6)] = x[rowbase * 64 + idx];
    Ws[idx] = ew0[idx];
  }
  if (tid < 64) bs[tid] = eb0[tid];
  __syncthreads();
  mlp_layer(acc, xs, Ws, bs, r, cg);             // h1
  __syncthreads();
#pragma unroll
  for (int i = 0; i < 16; ++i) {
    xs[(cg * 16 + i) * 65 + r] = acc[i];
    Ws[tid + 256 * i] = ew1[tid + 256 * i];
  }
  if (tid < 64) bs[tid] = eb1[tid];
  __syncthreads();
  mlp_layer(acc, xs, Ws, bs, r, cg);             // h2
  {
    float4* o4 = (float4*)(outA + (rowbase + r) * 64 + cg * 16);
#pragma unroll
    for (int q = 0; q < 4; ++q)
      o4[q] = make_float4(acc[q*4+0], acc[q*4+1], acc[q*4+2], acc[q*4+3]);
  }
  __syncthreads();
#pragma unroll
  for (int i = 0; i < 16; ++i) {
    xs[(cg * 16 + i) * 65 + r] = acc[i];
    Ws[tid + 256 * i] = wmm[tid + 256 * i];
  }
  if (tid < 64) bs[tid] = bmm[tid];
  __syncthreads();
  {   // flush AT (h2 transposed, feature-major)
    const size_t bb = rowbase >> 11;
    const int nbase = (int)(rowbase & 2047);
    const int c = tid >> 2, seg = tid & 3;
    float* oT = outAT + bb * 64 * N_NODES + (size_t)c * N_NODES + nbase + seg * 16;
#pragma unroll
    for (int q = 0; q < 4; ++q)
      ((float4*)oT)[q] = make_float4(xs[c*65+seg*16+q*4+0], xs[c*65+seg*16+q*4+1],
                                     xs[c*65+seg*16+q*4+2], xs[c*65+seg*16+q*4+3]);
  }
  mlp_layer(acc, xs, Ws, bs, r, cg);             // msg0
  {
    float4* o4 = (float4*)(outM + (rowbase + r) * 64 + cg * 16);
#pragma unroll
    for (int q = 0; q < 4; ++q)
      o4[q] = make_float4(acc[q*4+0], acc[q*4+1], acc[q*4+2], acc[q*4+3]);
  }
}

// plain single-layer linrelu (msg1)
__global__ __launch_bounds__(256) void linrelu_kernel(
    const float* __restrict__ in, const float* __restrict__ W,
    const float* __restrict__ bias, float* __restrict__ out)
{
  const int tid = threadIdx.x;
  const int r = tid & 63, cg = tid >> 6;
  const size_t rowbase = (size_t)blockIdx.x * 64;
  __shared__ float xs[64 * 65];
  __shared__ float Ws[64 * 64];
  __shared__ float bs[64];
  float acc[16];
#pragma unroll
  for (int i = 0; i < 16; ++i) {
    int idx = tid + 256 * i;
    xs[(idx & 63) * 65 + (idx >> 6)] = in[rowbase * 64 + idx];
    Ws[idx] = W[idx];
  }
  if (tid < 64) bs[tid] = bias[tid];
  __syncthreads();
  mlp_layer(acc, xs, Ws, bs, r, cg);
  float4* o4 = (float4*)(out + (rowbase + r) * 64 + cg * 16);
#pragma unroll
  for (int q = 0; q < 4; ++q)
    o4[q] = make_float4(acc[q*4+0], acc[q*4+1], acc[q*4+2], acc[q*4+3]);
}

// Fused mp: S = h_tile . h^T in LDS (Sbuf, ordered uints), 512 thr, ~78 KB LDS
// -> 2 blocks/CU. Wave-private top-50. Select re-reads Srow from LDS each level
// (hoist-proof: per-value work is two SGPR-bound compares on the fresh load;
// NO loop-invariant derived values — R9/R12 spill lesson). vals[32] loaded only
// at extraction, after select state is dead.
template <bool FINAL>
__global__ __launch_bounds__(512, 4) void mp_kernel(
    const float* __restrict__ h, const float* __restrict__ hT,
    const float* __restrict__ msg,
    const float* __restrict__ wu, const float* __restrict__ bu,
    float* __restrict__ outp, float* __restrict__ outT)
{
  const int tid = threadIdx.x;
  const int lane = tid & 63;
  const int w64 = tid >> 6;               // 8 waves <-> 8 rows
  const int bid = blockIdx.x;
  const int b = bid & 7;                  // round-robin blockIdx->XCD: 1 batch/XCD
  const int n0 = (bid >> 3) * 8;

  __shared__ unsigned Sbuf[8 * N_NODES];  // 64 KB ordered-uint S tile (+overlays)
  __shared__ unsigned hist[8][256];       // per-wave radix histograms (8 KB)
  __shared__ float hrL[8 * 64];           // MP epilogue row tile
  __shared__ unsigned LwMin[8][8], LwMax[8][8];   // [wave][row] prefilter staging
  __shared__ int   seli[8][52];
  __shared__ float selv[8][52];
  __shared__ int   eqlist[8][64];

  const float* hb  = h  + (size_t)b * N_NODES * 64;
  const float* hTb = hT + (size_t)b * 64 * N_NODES;
  const float* colp = hTb + 4 * tid;      // 512 threads x 4 cols = 2048

  // prefetch ring depth 4 (issued before anything else)
  float4 pf[4];
#pragma unroll
  for (int i = 0; i < 4; ++i) pf[i] = *(const float4*)(colp + (size_t)i * 2048);

  if (!FINAL) hrL[tid] = hb[(size_t)n0 * 64 + tid];
  for (int i = tid; i < 8 * 256; i += 512) (&hist[0][0])[i] = 0;

  // ---- FMA phase: acc2[r*2+(e>>1)][e&1] = S[r][4*tid+e]; rows via s_load
  v2f acc2[16];
#pragma unroll
  for (int i = 0; i < 16; ++i) { acc2[i][0] = 0.f; acc2[i][1] = 0.f; }

  const float* hrow = hb + (size_t)n0 * 64;        // block-uniform -> SGPR loads
  for (int k4 = 0; k4 < 16; ++k4) {
    float4 a[8];
#pragma unroll
    for (int r = 0; r < 8; ++r)
      a[r] = *(const float4*)(hrow + r * 64 + k4 * 4);
#pragma unroll
    for (int kk = 0; kk < 4; ++kk) {
      const int k = k4 * 4 + kk;
      float4 cu = pf[kk];
      if (k + 4 < 64) pf[kk] = *(const float4*)(colp + (size_t)(k + 4) * 2048);
      v2f c00 = {cu.x, cu.y}, c01 = {cu.z, cu.w};
#pragma unroll
      for (int r = 0; r < 8; ++r) {
        const float ar = ((const float*)&a[r])[kk];
        v2f as = {ar, ar};
        acc2[r*2+0] = __builtin_elementwise_fma(as, c00, acc2[r*2+0]);
        acc2[r*2+1] = __builtin_elementwise_fma(as, c01, acc2[r*2+1]);
      }
    }
  }

  // ---- convert, park in LDS, and compute reg-based prefilter reductions
#pragma unroll
  for (int r = 0; r < 8; ++r) {
    uint4 w;
    w.x = ford(acc2[r*2+0][0]); w.y = ford(acc2[r*2+0][1]);
    w.z = ford(acc2[r*2+1][0]); w.w = ford(acc2[r*2+1][1]);
    *(uint4*)&Sbuf[r * N_NODES + 4 * tid] = w;
    unsigned m1 = w.x > w.y ? w.x : w.y, m2 = w.z > w.w ? w.z : w.w;
    unsigned lm = m1 > m2 ? m1 : m2;           // per-lane max of its 4 vals
    unsigned mn = lm, mx = lm;
#pragma unroll
    for (int off = 32; off >= 1; off >>= 1) {
      unsigned o1 = (unsigned)__shfl_xor((int)mn, off, 64);
      unsigned o2 = (unsigned)__shfl_xor((int)mx, off, 64);
      mn = mn < o1 ? mn : o1;                  // wave-min of lane maxes
      mx = mx > o2 ? mx : o2;                  // wave-max
    }
    if (lane == 0) { LwMin[w64][r] = mn; LwMax[w64][r] = mx; }
  }
  __syncthreads();                             // barrier 1: Sbuf/LwMM/hrL ready

  // ======== wave-private selection: wave w64 owns row rw ========
  const int rw = w64;
  const unsigned* Srow = &Sbuf[rw * N_NODES];
  unsigned Lv, Tv;
  {
    unsigned lmn = (lane < 8) ? LwMin[lane][rw] : 0u;
    unsigned lmx = (lane < 8) ? LwMax[lane][rw] : 0u;
#pragma unroll
    for (int off = 4; off >= 1; off >>= 1) {
      unsigned o1 = (unsigned)__shfl_xor((int)lmn, off, 8);
      unsigned o2 = (unsigned)__shfl_xor((int)lmx, off, 8);
      lmn = lmn > o1 ? lmn : o1;               // L = max over waves of wave-mins
      lmx = lmx > o2 ? lmx : o2;               // M = row max
    }
    Lv = (unsigned)__shfl((int)lmn, 0, 64);
    unsigned Mv = (unsigned)__shfl((int)lmx, 0, 64);

    if (Lv == Mv) {
      Tv = Mv;                                 // >=64 copies of the max
    } else {
      int sh = 24 - 8 * (__builtin_clz(Lv ^ Mv) >> 3);
      unsigned pv = (unsigned)(((unsigned long long)Lv) >> (sh + 8));
      unsigned Kc = KSEL;
      int mode = 0;                            // 0=HIST 1=PROBE 2=DONE
      unsigned* hrw = hist[rw];
      for (int it = 0; it < 5 && mode != 2; ++it) {
        // wave-uniform candidate range for this level: prefix pv at bits
        // [31 : sh+8]  <=>  lo <= v <= hi  (two compares/value, hoist-proof)
        const int s2 = sh + 8;                 // 8..32
        const unsigned lo = (s2 >= 32) ? 0u : (pv << s2);
        const unsigned hi = (s2 >= 32) ? 0xFFFFFFFFu : (lo | ((1u << s2) - 1u));
        const unsigned lo2 = lo > Lv ? lo : Lv;
        if (mode == 0) {
#pragma unroll
          for (int i = 0; i < 8; ++i) {
            uint4 q = *(const uint4*)&Srow[i * 256 + 4 * lane];
            unsigned vv[4] = {q.x, q.y, q.z, q.w};
#pragma unroll
            for (int e = 0; e < 4; ++e) {
              unsigned v = vv[e];
              if (v >= lo2 && v <= hi)
                atomicAdd(&hrw[hidx1((v >> sh) & 255u)], 1u);
            }
          }
          uint4 q = *(const uint4*)&hrw[lane * 4];
          *(uint4*)&hrw[lane * 4] = make_uint4(0, 0, 0, 0);
          unsigned c0 = q.x, c1 = q.y, c2 = q.z, c3 = q.w;
          unsigned s0 = c0, s1 = c1, s2s = c2, s3 = c3;  // suffix over lanes
#pragma unroll
          for (int off = 1; off < 64; off <<= 1) {
            unsigned t0=__shfl_down((int)s0,off,64), t1=__shfl_down((int)s1,off,64);
            unsigned t2=__shfl_down((int)s2s,off,64), t3=__shfl_down((int)s3,off,64);
            if (lane + off < 64) { s0+=t0; s1+=t1; s2s+=t2; s3+=t3; }
          }
          unsigned T1=(unsigned)__shfl((int)s1,0,64);
          unsigned T2=(unsigned)__shfl((int)s2s,0,64);
          unsigned T3=(unsigned)__shfl((int)s3,0,64);
          unsigned cA[4] = {c0, c1, c2, c3};
          unsigned AA[4] = {s0 - c0 + T1 + T2 + T3, s1 - c1 + T2 + T3,
                            s2s - c2 + T3,          s3 - c3};
          int fg = -1;
#pragma unroll
          for (int g = 0; g < 4; ++g)
            if (AA[g] < Kc && Kc <= AA[g] + cA[g]) fg = g;
          unsigned long long mk = __ballot(fg >= 0);
          int src = __ffsll(mk) - 1;           // exactly one lane fires
          unsigned bin = 0, nKc = 0, cnt = 0;
          if (fg >= 0) {
            bin = (unsigned)(fg * 64 + lane);
            nKc = Kc - AA[fg];
            cnt = cA[fg];
          }
          bin = (unsigned)__shfl((int)bin, src, 64);
          nKc = (unsigned)__shfl((int)nKc, src, 64);
          cnt = (unsigned)__shfl((int)cnt, src, 64);
          pv = (pv << 8) | bin;
          Kc = nKc;
          sh -= 8;
          if (sh < 0)        { Tv = pv; mode = 2; }
          else if (cnt == 1) mode = 1;
        } else {
          // PROBE: the unique candidate in [lo2,hi] is T
          unsigned found = 0; bool has = false;
#pragma unroll
          for (int i = 0; i < 8; ++i) {
            uint4 q = *(const uint4*)&Srow[i * 256 + 4 * lane];
            unsigned vv[4] = {q.x, q.y, q.z, q.w};
#pragma unroll
            for (int e = 0; e < 4; ++e) {
              unsigned v = vv[e];
              if (v >= lo2 && v <= hi) { found = v; has = true; }
            }
          }
          unsigned long long mk = __ballot(has);
          int src = __ffsll(mk) - 1;
          Tv = (unsigned)__shfl((int)found, src, 64);
          mode = 2;
        }
      }
    }
  }

  // ---- extraction: load row once (select state now dead), counts + prefix scans
  unsigned vals[32];
  int cgt = 0, ceq = 0;
#pragma unroll
  for (int i = 0; i < 8; ++i) {
    uint4 q = *(const uint4*)&Srow[i * 256 + 4 * lane];
    vals[i*4+0] = q.x; vals[i*4+1] = q.y; vals[i*4+2] = q.z; vals[i*4+3] = q.w;
#pragma unroll
    for (int e = 0; e < 4; ++e) {
      cgt += (vals[i*4+e] > Tv);
      ceq += (vals[i*4+e] == Tv);
    }
  }
  int sg = cgt, se = ceq;
#pragma unroll
  for (int off = 1; off < 64; off <<= 1) {
    int t0 = __shfl_up(sg, off, 64), t1 = __shfl_up(se, off, 64);
    if (lane >= off) { sg += t0; se += t1; }
  }
  const int gW = __shfl(sg, 63, 64);           // total winners (> T), < 50
  const int eTot = __shfl(se, 63, 64);
  int gb = sg - cgt, eb = se - ceq;            // exclusive bases
#pragma unroll
  for (int i = 0; i < 8; ++i) {
#pragma unroll
    for (int e = 0; e < 4; ++e) {
      unsigned v = vals[i*4+e];
      int m = i * 256 + 4 * lane + e;
      if (v > Tv) { seli[rw][gb] = m; selv[rw][gb] = funord(v); ++gb; }
      else if (v == Tv) { if (eb < 64) eqlist[rw][eb] = m; ++eb; }
    }
  }
  const int eW = eTot < 64 ? eTot : 64;

  // ---- tie-resolve, wave-parallel: `need` smallest indices among equals
  const int needW = KSEL - gW;
  {
    const float Tf = funord(Tv);
    int myi = (lane < eW) ? eqlist[rw][lane] : 0x7FFFFFFF;
    for (int t = 0; t < needW; ++t) {
      int mn = myi;
#pragma unroll
      for (int off = 32; off >= 1; off >>= 1) {
        int o = __shfl_xor(mn, off, 64);
        mn = mn < o ? mn : o;
      }
      if (mn == 0x7FFFFFFF) break;
      if (myi == mn) {
        seli[rw][gW + t] = mn; selv[rw][gW + t] = Tf;
        myi = 0x7FFFFFFF;
      }
    }
  }

  if constexpr (FINAL) {
    float* ob = outp + ((size_t)b * N_NODES + n0 + rw) * N_NODES;
#pragma unroll
    for (int i = 0; i < 8; ++i) {
      float4 w; float* wf = (float*)&w;
#pragma unroll
      for (int e = 0; e < 4; ++e) {
        const unsigned v = vals[i*4+e];
        const int m = i * 256 + 4 * lane + e;
        bool keep = v > Tv;
        if (v == Tv) {
          for (int t = 0; t < needW; ++t)
            if (seli[rw][gW + t] == m) { keep = true; break; }
        }
        wf[e] = keep ? funord(v) : 0.f;
      }
      *(float4*)(ob + i * 256 + 4 * lane) = w;
    }
  } else {
    // aggregation into per-row Sbuf overlay (wave-private region)
    float* aggbR = (float*)&Sbuf[rw * N_NODES + 1024];
    {
      const float* msgb = msg + (size_t)b * N_NODES * 64;
      float a = 0.f;
      for (int i = 0; i < KSEL; ++i) {
        int mi = seli[rw][i];                  // wave-uniform LDS broadcast
        float vvv = selv[rw][i];
        a += vvv * msgb[(size_t)mi * 64 + lane];
      }
      aggbR[lane] = a;
    }
    // update MLP: h2[rw][lane]
    float s = bu[lane];
#pragma unroll 8
    for (int jj = 0; jj < 64; ++jj)
      s += hrL[rw * 64 + jj] * wu[jj * 64 + lane];
#pragma unroll 8
    for (int jj = 0; jj < 64; ++jj)
      s += aggbR[jj] * wu[(64 + jj) * 64 + lane];
    s = fmaxf(s, 0.f);
    outp[((size_t)b * N_NODES + n0 + rw) * 64 + lane] = s;
    __syncthreads();                           // all waves done with Sbuf
    float* otF = (float*)Sbuf;                 // transpose staging overlay
    otF[lane * 9 + rw] = s;                    // stride 9: conflict-free
    __syncthreads();
    {
      int f = tid >> 3, rr = tid & 7;
      outT[(size_t)b * 64 * N_NODES + (size_t)f * N_NODES + n0 + rr] = otF[f * 9 + rr];
    }
  }
}

extern "C" void kernel_launch(void* const* d_in, const int* in_sizes, int n_in,
                              void* d_out, int out_size, void* d_ws, size_t ws_size,
                              hipStream_t stream)
{
  (void)in_sizes; (void)n_in; (void)out_size; (void)ws_size;
  const float* x   = (const float*)d_in[0];
  const float* ew0 = (const float*)d_in[1];
  const float* eb0 = (const float*)d_in[2];
  const float* ew1 = (const float*)d_in[3];
  const float* eb1 = (const float*)d_in[4];
  const float* w0m = (const float*)d_in[5];
  const float* b0m = (const float*)d_in[6];
  const float* w0u = (const float*)d_in[7];
  const float* b0u = (const float*)d_in[8];
  const float* w1m = (const float*)d_in[9];
  const float* b1m = (const float*)d_in[10];
  const float* w1u = (const float*)d_in[11];
  const float* b1u = (const float*)d_in[12];
  float* out = (float*)d_out;
  float* ws = (float*)d_ws;

  const size_t BUF = (size_t)8 * N_NODES * 64;  // 4 MB each, 20 MB total ws
  float* A   = ws;
  float* AT  = ws + 1 * BUF;
  float* Bf  = ws + 2 * BUF;
  float* BfT = ws + 3 * BUF;
  float* C   = ws + 4 * BUF;

  // fused embedding (2 layers) + msg0
  emb3_kernel<<<256, 256, 0, stream>>>(x, ew0, eb0, ew1, eb1, w0m, b0m, A, AT, C);

  // MP layer 0 (consumes msg0=C, produces Bf/BfT)
  mp_kernel<false><<<2048, 512, 0, stream>>>(A, AT, C, w0u, b0u, Bf, BfT);

  // msg1
  linrelu_kernel<<<256, 256, 0, stream>>>(Bf, w1m, b1m, C);

  // MP layer 1
  mp_kernel<false><<<2048, 512, 0, stream>>>(Bf, BfT, C, w1u, b1u, A, AT);

  // final dense top-k adjacency
  mp_kernel<true><<<2048, 512, 0, stream>>>(A, AT, nullptr, nullptr, nullptr, out, nullptr);
}

// Round 14
// 546.684 us; speedup vs baseline: 5.2745x; 1.1149x over previous
//
#include <hip/hip_runtime.h>

#define N_NODES 2048
#define KSEL 50
#define ROWS 4

typedef float v2f __attribute__((ext_vector_type(2)));

// ---- order-preserving fp32 <-> uint map (monotone: bigger float => bigger uint)
__device__ __forceinline__ unsigned ford(float f) {
  unsigned b = __float_as_uint(f);
  return b ^ ((b & 0x80000000u) ? 0xFFFFFFFFu : 0x80000000u);
}
__device__ __forceinline__ float funord(unsigned u) {
  unsigned b = (u & 0x80000000u) ? (u ^ 0x80000000u) : ~u;
  return __uint_as_float(b);
}

// 1-sub-counter hist layout: bin b -> word ((b&63)<<2)|(b>>6).
// Scan: lane reads uint4 at [lane*4] = bins {g*64+lane}, g=0..3 (components).
__device__ __forceinline__ int hidx1(unsigned b) {
  return (int)(((b & 63u) << 2) | (b >> 6));
}

// shared single-layer MLP tile: acc[16] = relu(bias + xs^T W), xs transposed layout
__device__ __forceinline__ void mlp_layer(float acc[16], const float* xs,
                                          const float* Ws, const float* bs,
                                          int r, int cg) {
  const float4* Ws4 = (const float4*)Ws;
#pragma unroll
  for (int i = 0; i < 16; ++i) acc[i] = bs[cg * 16 + i];
#pragma unroll 8
  for (int k = 0; k < 64; ++k) {
    float xv = xs[k * 65 + r];
    float4 w0 = Ws4[k * 16 + cg * 4 + 0];
    float4 w1 = Ws4[k * 16 + cg * 4 + 1];
    float4 w2 = Ws4[k * 16 + cg * 4 + 2];
    float4 w3 = Ws4[k * 16 + cg * 4 + 3];
    acc[0]  += xv * w0.x; acc[1]  += xv * w0.y; acc[2]  += xv * w0.z; acc[3]  += xv * w0.w;
    acc[4]  += xv * w1.x; acc[5]  += xv * w1.y; acc[6]  += xv * w1.z; acc[7]  += xv * w1.w;
    acc[8]  += xv * w2.x; acc[9]  += xv * w2.y; acc[10] += xv * w2.z; acc[11] += xv * w2.w;
    acc[12] += xv * w3.x; acc[13] += xv * w3.y; acc[14] += xv * w3.z; acc[15] += xv * w3.w;
  }
#pragma unroll
  for (int i = 0; i < 16; ++i) acc[i] = fmaxf(acc[i], 0.f);
}

// Fused embedding: h1=relu(x@w0+b0); h2=relu(h1@w1+b1) -> A, AT; msg0=relu(h2@wm+bm) -> M
__global__ __launch_bounds__(256) void emb3_kernel(
    const float* __restrict__ x,
    const float* __restrict__ ew0, const float* __restrict__ eb0,
    const float* __restrict__ ew1, const float* __restrict__ eb1,
    const float* __restrict__ wmm, const float* __restrict__ bmm,
    float* __restrict__ outA, float* __restrict__ outAT, float* __restrict__ outM)
{
  const int tid = threadIdx.x;
  const int r = tid & 63, cg = tid >> 6;
  const size_t rowbase = (size_t)blockIdx.x * 64;
  __shared__ float xs[64 * 65];
  __shared__ float Ws[64 * 64];
  __shared__ float bs[64];
  float acc[16];

#pragma unroll
  for (int i = 0; i < 16; ++i) {
    int idx = tid + 256 * i;
    xs[(idx & 63) * 65 + (idx >> 6)] = x[rowbase * 64 + idx];
    Ws[idx] = ew0[idx];
  }
  if (tid < 64) bs[tid] = eb0[tid];
  __syncthreads();
  mlp_layer(acc, xs, Ws, bs, r, cg);             // h1
  __syncthreads();
#pragma unroll
  for (int i = 0; i < 16; ++i) {
    xs[(cg * 16 + i) * 65 + r] = acc[i];
    Ws[tid + 256 * i] = ew1[tid + 256 * i];
  }
  if (tid < 64) bs[tid] = eb1[tid];
  __syncthreads();
  mlp_layer(acc, xs, Ws, bs, r, cg);             // h2
  {
    float4* o4 = (float4*)(outA + (rowbase + r) * 64 + cg * 16);
#pragma unroll
    for (int q = 0; q < 4; ++q)
      o4[q] = make_float4(acc[q*4+0], acc[q*4+1], acc[q*4+2], acc[q*4+3]);
  }
  __syncthreads();
#pragma unroll
  for (int i = 0; i < 16; ++i) {
    xs[(cg * 16 + i) * 65 + r] = acc[i];
    Ws[tid + 256 * i] = wmm[tid + 256 * i];
  }
  if (tid < 64) bs[tid] = bmm[tid];
  __syncthreads();
  {   // flush AT (h2 transposed, feature-major)
    const size_t bb = rowbase >> 11;
    const int nbase = (int)(rowbase & 2047);
    const int c = tid >> 2, seg = tid & 3;
    float* oT = outAT + bb * 64 * N_NODES + (size_t)c * N_NODES + nbase + seg * 16;
#pragma unroll
    for (int q = 0; q < 4; ++q)
      ((float4*)oT)[q] = make_float4(xs[c*65+seg*16+q*4+0], xs[c*65+seg*16+q*4+1],
                                     xs[c*65+seg*16+q*4+2], xs[c*65+seg*16+q*4+3]);
  }
  mlp_layer(acc, xs, Ws, bs, r, cg);             // msg0
  {
    float4* o4 = (float4*)(outM + (rowbase + r) * 64 + cg * 16);
#pragma unroll
    for (int q = 0; q < 4; ++q)
      o4[q] = make_float4(acc[q*4+0], acc[q*4+1], acc[q*4+2], acc[q*4+3]);
  }
}

// plain single-layer linrelu (msg1)
__global__ __launch_bounds__(256) void linrelu_kernel(
    const float* __restrict__ in, const float* __restrict__ W,
    const float* __restrict__ bias, float* __restrict__ out)
{
  const int tid = threadIdx.x;
  const int r = tid & 63, cg = tid >> 6;
  const size_t rowbase = (size_t)blockIdx.x * 64;
  __shared__ float xs[64 * 65];
  __shared__ float Ws[64 * 64];
  __shared__ float bs[64];
  float acc[16];
#pragma unroll
  for (int i = 0; i < 16; ++i) {
    int idx = tid + 256 * i;
    xs[(idx & 63) * 65 + (idx >> 6)] = in[rowbase * 64 + idx];
    Ws[idx] = W[idx];
  }
  if (tid < 64) bs[tid] = bias[tid];
  __syncthreads();
  mlp_layer(acc, xs, Ws, bs, r, cg);
  float4* o4 = (float4*)(out + (rowbase + r) * 64 + cg * 16);
#pragma unroll
  for (int q = 0; q < 4; ++q)
    o4[q] = make_float4(acc[q*4+0], acc[q*4+1], acc[q*4+2], acc[q*4+3]);
}

// Fused mp, 4-row/256-thread blocks (4096 blocks): S tile in LDS (~40 KB total
// -> 4 blocks/CU for phase-staggered overlap). Wave-private top-50 (wave r owns
// row r). Select re-reads Srow from LDS each level (hoist-proof two-compare
// range test; NO loop-invariant per-value work — R9/R12 spill lesson).
// vals[32] loaded only at extraction, after select state is dead; FINAL write
// fused into extraction.
template <bool FINAL>
__global__ __launch_bounds__(256, 4) void mp_kernel(
    const float* __restrict__ h, const float* __restrict__ hT,
    const float* __restrict__ msg,
    const float* __restrict__ wu, const float* __restrict__ bu,
    float* __restrict__ outp, float* __restrict__ outT)
{
  const int tid = threadIdx.x;
  const int lane = tid & 63;
  const int w64 = tid >> 6;               // 4 waves <-> 4 rows
  const int bid = blockIdx.x;
  const int b = bid & 7;                  // round-robin blockIdx->XCD: 1 batch/XCD
  const int n0 = (bid >> 3) * ROWS;

  __shared__ unsigned Sbuf[ROWS * N_NODES];   // 32 KB ordered-uint S tile
  __shared__ unsigned hist[ROWS][256];        // 4 KB radix histograms
  __shared__ float    hrL[ROWS * 64];         // 1 KB epilogue row tile
  __shared__ unsigned LwMin[ROWS][ROWS], LwMax[ROWS][ROWS];
  __shared__ int   seli[ROWS][52];
  __shared__ float selv[ROWS][52];
  __shared__ int   eqlist[ROWS][56];

  const float* hb  = h  + (size_t)b * N_NODES * 64;
  const float* hTb = hT + (size_t)b * 64 * N_NODES;
  const float* colp = hTb + 4 * tid;      // group A: cols 4*tid..+3; B at +1024

  // prefetch ring depth 4 per group (issued before anything else)
  float4 pfA[4], pfB[4];
#pragma unroll
  for (int i = 0; i < 4; ++i) {
    pfA[i] = *(const float4*)(colp + (size_t)i * 2048);
    pfB[i] = *(const float4*)(colp + (size_t)i * 2048 + 1024);
  }

  if (!FINAL) hrL[tid] = hb[(size_t)n0 * 64 + tid];    // ROWS*64 == 256
  for (int i = tid; i < ROWS * 256; i += 256) (&hist[0][0])[i] = 0;

  // ---- FMA phase: acc2[r*4+q]: q=0,1 -> group A pairs; q=2,3 -> group B pairs
  v2f acc2[16];
#pragma unroll
  for (int i = 0; i < 16; ++i) { acc2[i][0] = 0.f; acc2[i][1] = 0.f; }

  const float* hrow = hb + (size_t)n0 * 64;            // block-uniform -> SGPR
  for (int k4 = 0; k4 < 16; ++k4) {
    float4 a[ROWS];
#pragma unroll
    for (int r = 0; r < ROWS; ++r)
      a[r] = *(const float4*)(hrow + r * 64 + k4 * 4);
#pragma unroll
    for (int kk = 0; kk < 4; ++kk) {
      const int k = k4 * 4 + kk;
      float4 cA = pfA[kk], cB = pfB[kk];               // ring: kk == k&3
      if (k + 4 < 64) {
        pfA[kk] = *(const float4*)(colp + (size_t)(k + 4) * 2048);
        pfB[kk] = *(const float4*)(colp + (size_t)(k + 4) * 2048 + 1024);
      }
      v2f cA0 = {cA.x, cA.y}, cA1 = {cA.z, cA.w};
      v2f cB0 = {cB.x, cB.y}, cB1 = {cB.z, cB.w};
#pragma unroll
      for (int r = 0; r < ROWS; ++r) {
        const float ar = ((const float*)&a[r])[kk];
        v2f as = {ar, ar};
        acc2[r*4+0] = __builtin_elementwise_fma(as, cA0, acc2[r*4+0]);
        acc2[r*4+1] = __builtin_elementwise_fma(as, cA1, acc2[r*4+1]);
        acc2[r*4+2] = __builtin_elementwise_fma(as, cB0, acc2[r*4+2]);
        acc2[r*4+3] = __builtin_elementwise_fma(as, cB1, acc2[r*4+3]);
      }
    }
  }

  // ---- convert, park in LDS, reg-based prefilter reductions
#pragma unroll
  for (int r = 0; r < ROWS; ++r) {
    uint4 wA, wB;
    wA.x = ford(acc2[r*4+0][0]); wA.y = ford(acc2[r*4+0][1]);
    wA.z = ford(acc2[r*4+1][0]); wA.w = ford(acc2[r*4+1][1]);
    wB.x = ford(acc2[r*4+2][0]); wB.y = ford(acc2[r*4+2][1]);
    wB.z = ford(acc2[r*4+3][0]); wB.w = ford(acc2[r*4+3][1]);
    *(uint4*)&Sbuf[r * N_NODES + 4 * tid] = wA;
    *(uint4*)&Sbuf[r * N_NODES + 1024 + 4 * tid] = wB;
    unsigned mA1 = wA.x > wA.y ? wA.x : wA.y, mA2 = wA.z > wA.w ? wA.z : wA.w;
    unsigned mB1 = wB.x > wB.y ? wB.x : wB.y, mB2 = wB.z > wB.w ? wB.z : wB.w;
    unsigned mA = mA1 > mA2 ? mA1 : mA2, mB = mB1 > mB2 ? mB1 : mB2;
    unsigned lm = mA > mB ? mA : mB;           // per-lane max of its 8 vals
    unsigned mn = lm, mx = lm;
#pragma unroll
    for (int off = 32; off >= 1; off >>= 1) {
      unsigned o1 = (unsigned)__shfl_xor((int)mn, off, 64);
      unsigned o2 = (unsigned)__shfl_xor((int)mx, off, 64);
      mn = mn < o1 ? mn : o1;                  // wave-min of lane maxes
      mx = mx > o2 ? mx : o2;                  // wave-max
    }
    if (lane == 0) { LwMin[w64][r] = mn; LwMax[w64][r] = mx; }
  }
  __syncthreads();                             // barrier 1: Sbuf/LwMM/hrL ready

  // ======== wave-private selection: wave w64 owns row rw ========
  const int rw = w64;
  const unsigned* Srow = &Sbuf[rw * N_NODES];
  unsigned Lv, Tv;
  {
    unsigned lmn = (lane < ROWS) ? LwMin[lane][rw] : 0u;
    unsigned lmx = (lane < ROWS) ? LwMax[lane][rw] : 0u;
#pragma unroll
    for (int off = 2; off >= 1; off >>= 1) {
      unsigned o1 = (unsigned)__shfl_xor((int)lmn, off, 4);
      unsigned o2 = (unsigned)__shfl_xor((int)lmx, off, 4);
      lmn = lmn > o1 ? lmn : o1;               // L = max over waves of wave-mins
      lmx = lmx > o2 ? lmx : o2;               // M = row max
    }
    Lv = (unsigned)__shfl((int)lmn, 0, 64);
    unsigned Mv = (unsigned)__shfl((int)lmx, 0, 64);

    if (Lv == Mv) {
      Tv = Mv;                                 // >=64 copies of the max
    } else {
      int sh = 24 - 8 * (__builtin_clz(Lv ^ Mv) >> 3);
      unsigned pv = (unsigned)(((unsigned long long)Lv) >> (sh + 8));
      unsigned Kc = KSEL;
      int mode = 0;                            // 0=HIST 1=PROBE 2=DONE
      unsigned* hrw = hist[rw];
      for (int it = 0; it < 5 && mode != 2; ++it) {
        // wave-uniform candidate range: prefix pv at bits [31 : sh+8]
        // <=> lo2 <= v <= hi  (two compares/value, hoist-proof)
        const int s2 = sh + 8;                 // 8..32
        const unsigned lo = (s2 >= 32) ? 0u : (pv << s2);
        const unsigned hi = (s2 >= 32) ? 0xFFFFFFFFu : (lo | ((1u << s2) - 1u));
        const unsigned lo2 = lo > Lv ? lo : Lv;
        if (mode == 0) {
#pragma unroll
          for (int i = 0; i < 8; ++i) {
            uint4 q = *(const uint4*)&Srow[i * 256 + 4 * lane];
            unsigned vv[4] = {q.x, q.y, q.z, q.w};
#pragma unroll
            for (int e = 0; e < 4; ++e) {
              unsigned v = vv[e];
              if (v >= lo2 && v <= hi)
                atomicAdd(&hrw[hidx1((v >> sh) & 255u)], 1u);
            }
          }
          uint4 q = *(const uint4*)&hrw[lane * 4];
          *(uint4*)&hrw[lane * 4] = make_uint4(0, 0, 0, 0);
          unsigned c0 = q.x, c1 = q.y, c2 = q.z, c3 = q.w;
          unsigned s0 = c0, s1 = c1, s2s = c2, s3 = c3;  // suffix over lanes
#pragma unroll
          for (int off = 1; off < 64; off <<= 1) {
            unsigned t0=__shfl_down((int)s0,off,64), t1=__shfl_down((int)s1,off,64);
            unsigned t2=__shfl_down((int)s2s,off,64), t3=__shfl_down((int)s3,off,64);
            if (lane + off < 64) { s0+=t0; s1+=t1; s2s+=t2; s3+=t3; }
          }
          unsigned T1=(unsigned)__shfl((int)s1,0,64);
          unsigned T2=(unsigned)__shfl((int)s2s,0,64);
          unsigned T3=(unsigned)__shfl((int)s3,0,64);
          unsigned cA4[4] = {c0, c1, c2, c3};
          unsigned AA[4] = {s0 - c0 + T1 + T2 + T3, s1 - c1 + T2 + T3,
                            s2s - c2 + T3,          s3 - c3};
          int fg = -1;
#pragma unroll
          for (int g = 0; g < 4; ++g)
            if (AA[g] < Kc && Kc <= AA[g] + cA4[g]) fg = g;
          unsigned long long mk = __ballot(fg >= 0);
          int src = __ffsll(mk) - 1;           // exactly one lane fires
          unsigned bin = 0, nKc = 0, cnt = 0;
          if (fg >= 0) {
            bin = (unsigned)(fg * 64 + lane);
            nKc = Kc - AA[fg];
            cnt = cA4[fg];
          }
          bin = (unsigned)__shfl((int)bin, src, 64);
          nKc = (unsigned)__shfl((int)nKc, src, 64);
          cnt = (unsigned)__shfl((int)cnt, src, 64);
          pv = (pv << 8) | bin;
          Kc = nKc;
          sh -= 8;
          if (sh < 0)        { Tv = pv; mode = 2; }
          else if (cnt == 1) mode = 1;
        } else {
          // PROBE: the unique candidate in [lo2,hi] is T
          unsigned found = 0; bool has = false;
#pragma unroll
          for (int i = 0; i < 8; ++i) {
            uint4 q = *(const uint4*)&Srow[i * 256 + 4 * lane];
            unsigned vv[4] = {q.x, q.y, q.z, q.w};
#pragma unroll
            for (int e = 0; e < 4; ++e) {
              unsigned v = vv[e];
              if (v >= lo2 && v <= hi) { found = v; has = true; }
            }
          }
          unsigned long long mk = __ballot(has);
          int src = __ffsll(mk) - 1;
          Tv = (unsigned)__shfl((int)found, src, 64);
          mode = 2;
        }
      }
    }
  }

  // ---- extraction: load row once (select state dead), counts + prefix scans
  unsigned vals[32];
  int cgt = 0, ceq = 0;
#pragma unroll
  for (int i = 0; i < 8; ++i) {
    uint4 q = *(const uint4*)&Srow[i * 256 + 4 * lane];
    vals[i*4+0] = q.x; vals[i*4+1] = q.y; vals[i*4+2] = q.z; vals[i*4+3] = q.w;
#pragma unroll
    for (int e = 0; e < 4; ++e) {
      cgt += (vals[i*4+e] > Tv);
      ceq += (vals[i*4+e] == Tv);
    }
  }
  int sg = cgt, se = ceq;
#pragma unroll
  for (int off = 1; off < 64; off <<= 1) {
    int t0 = __shfl_up(sg, off, 64), t1 = __shfl_up(se, off, 64);
    if (lane >= off) { sg += t0; se += t1; }
  }
  const int gW = __shfl(sg, 63, 64);           // total winners (> T), < 50
  const int eTot = __shfl(se, 63, 64);
  int gb = sg - cgt, eb = se - ceq;            // exclusive bases

  float* ob = FINAL ? (outp + ((size_t)b * N_NODES + n0 + rw) * N_NODES) : nullptr;
  if constexpr (FINAL) {
    // masked dense write fused with extraction; ties fixed up after resolve
#pragma unroll
    for (int i = 0; i < 8; ++i) {
      float4 w; float* wf = (float*)&w;
#pragma unroll
      for (int e = 0; e < 4; ++e) {
        unsigned v = vals[i*4+e];
        wf[e] = (v > Tv) ? funord(v) : 0.f;
        if (v == Tv) { if (eb < 56) eqlist[rw][eb] = i * 256 + 4 * lane + e; ++eb; }
      }
      *(float4*)(ob + i * 256 + 4 * lane) = w;
    }
  } else {
#pragma unroll
    for (int i = 0; i < 8; ++i) {
#pragma unroll
      for (int e = 0; e < 4; ++e) {
        unsigned v = vals[i*4+e];
        int m = i * 256 + 4 * lane + e;
        if (v > Tv) { seli[rw][gb] = m; selv[rw][gb] = funord(v); ++gb; }
        else if (v == Tv) { if (eb < 56) eqlist[rw][eb] = m; ++eb; }
      }
    }
  }
  const int eW = eTot < 56 ? eTot : 56;

  // ---- tie-resolve, wave-parallel: `need` smallest indices among equals
  const int needW = KSEL - gW;
  const float Tf = funord(Tv);
  {
    int myi = (lane < eW) ? eqlist[rw][lane] : 0x7FFFFFFF;
    for (int t = 0; t < needW; ++t) {
      int mn = myi;
#pragma unroll
      for (int off = 32; off >= 1; off >>= 1) {
        int o = __shfl_xor(mn, off, 64);
        mn = mn < o ? mn : o;
      }
      if (mn == 0x7FFFFFFF) break;
      if (myi == mn) {
        if (!FINAL) { seli[rw][gW + t] = mn; selv[rw][gW + t] = Tf; }
        else eqlist[rw][t] = mn;               // reuse as fixup list
        myi = 0x7FFFFFFF;
      }
    }
  }

  if constexpr (FINAL) {
    if (lane < needW) ob[eqlist[rw][lane]] = Tf;         // tie fixups
  } else {
    // aggregation into per-row Sbuf overlay (wave-private region; row is dead)
    float* aggbR = (float*)&Sbuf[rw * N_NODES + 1024];
    {
      const float* msgb = msg + (size_t)b * N_NODES * 64;
      float a = 0.f;
      for (int i = 0; i < KSEL; ++i) {
        int mi = seli[rw][i];                  // wave-uniform LDS broadcast
        float vvv = selv[rw][i];
        a += vvv * msgb[(size_t)mi * 64 + lane];
      }
      aggbR[lane] = a;
    }
    // update MLP: h2[rw][lane]
    float s = bu[lane];
#pragma unroll 8
    for (int jj = 0; jj < 64; ++jj)
      s += hrL[rw * 64 + jj] * wu[jj * 64 + lane];
#pragma unroll 8
    for (int jj = 0; jj < 64; ++jj)
      s += aggbR[jj] * wu[(64 + jj) * 64 + lane];
    s = fmaxf(s, 0.f);
    outp[((size_t)b * N_NODES + n0 + rw) * 64 + lane] = s;
    __syncthreads();                           // all waves done with Sbuf
    float* otF = (float*)Sbuf;                 // transpose staging overlay
    otF[lane * 9 + rw] = s;                    // stride 9: conflict-free
    __syncthreads();
    {                                          // flush h2T: 64 feats x 4 rows
      int f = tid >> 2, rr = tid & 3;
      outT[(size_t)b * 64 * N_NODES + (size_t)f * N_NODES + n0 + rr] = otF[f * 9 + rr];
    }
  }
}

extern "C" void kernel_launch(void* const* d_in, const int* in_sizes, int n_in,
                              void* d_out, int out_size, void* d_ws, size_t ws_size,
                              hipStream_t stream)
{
  (void)in_sizes; (void)n_in; (void)out_size; (void)ws_size;
  const float* x   = (const float*)d_in[0];
  const float* ew0 = (const float*)d_in[1];
  const float* eb0 = (const float*)d_in[2];
  const float* ew1 = (const float*)d_in[3];
  const float* eb1 = (const float*)d_in[4];
  const float* w0m = (const float*)d_in[5];
  const float* b0m = (const float*)d_in[6];
  const float* w0u = (const float*)d_in[7];
  const float* b0u = (const float*)d_in[8];
  const float* w1m = (const float*)d_in[9];
  const float* b1m = (const float*)d_in[10];
  const float* w1u = (const float*)d_in[11];
  const float* b1u = (const float*)d_in[12];
  float* out = (float*)d_out;
  float* ws = (float*)d_ws;

  const size_t BUF = (size_t)8 * N_NODES * 64;  // 4 MB each, 20 MB total ws
  float* A   = ws;
  float* AT  = ws + 1 * BUF;
  float* Bf  = ws + 2 * BUF;
  float* BfT = ws + 3 * BUF;
  float* C   = ws + 4 * BUF;

  const int NBLK = 8 * (N_NODES / ROWS);        // 4096

  // fused embedding (2 layers) + msg0
  emb3_kernel<<<256, 256, 0, stream>>>(x, ew0, eb0, ew1, eb1, w0m, b0m, A, AT, C);

  // MP layer 0 (consumes msg0=C, produces Bf/BfT)
  mp_kernel<false><<<NBLK, 256, 0, stream>>>(A, AT, C, w0u, b0u, Bf, BfT);

  // msg1
  linrelu_kernel<<<256, 256, 0, stream>>>(Bf, w1m, b1m, C);

  // MP layer 1
  mp_kernel<false><<<NBLK, 256, 0, stream>>>(Bf, BfT, C, w1u, b1u, A, AT);

  // final dense top-k adjacency
  mp_kernel<true><<<NBLK, 256, 0, stream>>>(A, AT, nullptr, nullptr, nullptr, out, nullptr);
}

// Round 15
// 540.513 us; speedup vs baseline: 5.3347x; 1.0114x over previous
//
#include <hip/hip_runtime.h>

#define N_NODES 2048
#define KSEL 50
#define ROWS 4

typedef float v2f __attribute__((ext_vector_type(2)));

// ---- order-preserving fp32 <-> uint map (monotone: bigger float => bigger uint)
__device__ __forceinline__ unsigned ford(float f) {
  unsigned b = __float_as_uint(f);
  return b ^ ((b & 0x80000000u) ? 0xFFFFFFFFu : 0x80000000u);
}
__device__ __forceinline__ float funord(unsigned u) {
  unsigned b = (u & 0x80000000u) ? (u ^ 0x80000000u) : ~u;
  return __uint_as_float(b);
}

// 1-sub-counter hist layout: bin b -> word ((b&63)<<2)|(b>>6).
// Scan: lane reads uint4 at [lane*4] = bins {g*64+lane}, g=0..3 (components).
__device__ __forceinline__ int hidx1(unsigned b) {
  return (int)(((b & 63u) << 2) | (b >> 6));
}

// shared single-layer MLP tile: acc[16] = relu(bias + xs^T W), xs transposed layout
__device__ __forceinline__ void mlp_layer(float acc[16], const float* xs,
                                          const float* Ws, const float* bs,
                                          int r, int cg) {
  const float4* Ws4 = (const float4*)Ws;
#pragma unroll
  for (int i = 0; i < 16; ++i) acc[i] = bs[cg * 16 + i];
#pragma unroll 8
  for (int k = 0; k < 64; ++k) {
    float xv = xs[k * 65 + r];
    float4 w0 = Ws4[k * 16 + cg * 4 + 0];
    float4 w1 = Ws4[k * 16 + cg * 4 + 1];
    float4 w2 = Ws4[k * 16 + cg * 4 + 2];
    float4 w3 = Ws4[k * 16 + cg * 4 + 3];
    acc[0]  += xv * w0.x; acc[1]  += xv * w0.y; acc[2]  += xv * w0.z; acc[3]  += xv * w0.w;
    acc[4]  += xv * w1.x; acc[5]  += xv * w1.y; acc[6]  += xv * w1.z; acc[7]  += xv * w1.w;
    acc[8]  += xv * w2.x; acc[9]  += xv * w2.y; acc[10] += xv * w2.z; acc[11] += xv * w2.w;
    acc[12] += xv * w3.x; acc[13] += xv * w3.y; acc[14] += xv * w3.z; acc[15] += xv * w3.w;
  }
#pragma unroll
  for (int i = 0; i < 16; ++i) acc[i] = fmaxf(acc[i], 0.f);
}

// Fused embedding: h1=relu(x@w0+b0); h2=relu(h1@w1+b1) -> A, AT; msg0=relu(h2@wm+bm) -> M
__global__ __launch_bounds__(256) void emb3_kernel(
    const float* __restrict__ x,
    const float* __restrict__ ew0, const float* __restrict__ eb0,
    const float* __restrict__ ew1, const float* __restrict__ eb1,
    const float* __restrict__ wmm, const float* __restrict__ bmm,
    float* __restrict__ outA, float* __restrict__ outAT, float* __restrict__ outM)
{
  const int tid = threadIdx.x;
  const int r = tid & 63, cg = tid >> 6;
  const size_t rowbase = (size_t)blockIdx.x * 64;
  __shared__ float xs[64 * 65];
  __shared__ float Ws[64 * 64];
  __shared__ float bs[64];
  float acc[16];

#pragma unroll
  for (int i = 0; i < 16; ++i) {
    int idx = tid + 256 * i;
    xs[(idx & 63) * 65 + (idx >> 6)] = x[rowbase * 64 + idx];
    Ws[idx] = ew0[idx];
  }
  if (tid < 64) bs[tid] = eb0[tid];
  __syncthreads();
  mlp_layer(acc, xs, Ws, bs, r, cg);             // h1
  __syncthreads();
#pragma unroll
  for (int i = 0; i < 16; ++i) {
    xs[(cg * 16 + i) * 65 + r] = acc[i];
    Ws[tid + 256 * i] = ew1[tid + 256 * i];
  }
  if (tid < 64) bs[tid] = eb1[tid];
  __syncthreads();
  mlp_layer(acc, xs, Ws, bs, r, cg);             // h2
  {
    float4* o4 = (float4*)(outA + (rowbase + r) * 64 + cg * 16);
#pragma unroll
    for (int q = 0; q < 4; ++q)
      o4[q] = make_float4(acc[q*4+0], acc[q*4+1], acc[q*4+2], acc[q*4+3]);
  }
  __syncthreads();
#pragma unroll
  for (int i = 0; i < 16; ++i) {
    xs[(cg * 16 + i) * 65 + r] = acc[i];
    Ws[tid + 256 * i] = wmm[tid + 256 * i];
  }
  if (tid < 64) bs[tid] = bmm[tid];
  __syncthreads();
  {   // flush AT (h2 transposed, feature-major)
    const size_t bb = rowbase >> 11;
    const int nbase = (int)(rowbase & 2047);
    const int c = tid >> 2, seg = tid & 3;
    float* oT = outAT + bb * 64 * N_NODES + (size_t)c * N_NODES + nbase + seg * 16;
#pragma unroll
    for (int q = 0; q < 4; ++q)
      ((float4*)oT)[q] = make_float4(xs[c*65+seg*16+q*4+0], xs[c*65+seg*16+q*4+1],
                                     xs[c*65+seg*16+q*4+2], xs[c*65+seg*16+q*4+3]);
  }
  mlp_layer(acc, xs, Ws, bs, r, cg);             // msg0
  {
    float4* o4 = (float4*)(outM + (rowbase + r) * 64 + cg * 16);
#pragma unroll
    for (int q = 0; q < 4; ++q)
      o4[q] = make_float4(acc[q*4+0], acc[q*4+1], acc[q*4+2], acc[q*4+3]);
  }
}

// plain single-layer linrelu (msg1)
__global__ __launch_bounds__(256) void linrelu_kernel(
    const float* __restrict__ in, const float* __restrict__ W,
    const float* __restrict__ bias, float* __restrict__ out)
{
  const int tid = threadIdx.x;
  const int r = tid & 63, cg = tid >> 6;
  const size_t rowbase = (size_t)blockIdx.x * 64;
  __shared__ float xs[64 * 65];
  __shared__ float Ws[64 * 64];
  __shared__ float bs[64];
  float acc[16];
#pragma unroll
  for (int i = 0; i < 16; ++i) {
    int idx = tid + 256 * i;
    xs[(idx & 63) * 65 + (idx >> 6)] = in[rowbase * 64 + idx];
    Ws[idx] = W[idx];
  }
  if (tid < 64) bs[tid] = bias[tid];
  __syncthreads();
  mlp_layer(acc, xs, Ws, bs, r, cg);
  float4* o4 = (float4*)(out + (rowbase + r) * 64 + cg * 16);
#pragma unroll
  for (int q = 0; q < 4; ++q)
    o4[q] = make_float4(acc[q*4+0], acc[q*4+1], acc[q*4+2], acc[q*4+3]);
}

// Fused mp, 4-row/256-thread blocks (4096 blocks): S tile in LDS (~40 KB total
// -> 4 blocks/CU phase-staggered). Wave-private top-50 (wave r owns row r).
// Select re-reads Srow from LDS each level (hoist-proof two-compare range
// test; NO loop-invariant per-value work — R9/R12 spill lesson). R15: SGPR
// row-operand double-buffer, batched aggregation gather, dual FMA chains.
template <bool FINAL>
__global__ __launch_bounds__(256, 4) void mp_kernel(
    const float* __restrict__ h, const float* __restrict__ hT,
    const float* __restrict__ msg,
    const float* __restrict__ wu, const float* __restrict__ bu,
    float* __restrict__ outp, float* __restrict__ outT)
{
  const int tid = threadIdx.x;
  const int lane = tid & 63;
  const int w64 = tid >> 6;               // 4 waves <-> 4 rows
  const int bid = blockIdx.x;
  const int b = bid & 7;                  // round-robin blockIdx->XCD: 1 batch/XCD
  const int n0 = (bid >> 3) * ROWS;

  __shared__ unsigned Sbuf[ROWS * N_NODES];   // 32 KB ordered-uint S tile
  __shared__ unsigned hist[ROWS][256];        // 4 KB radix histograms
  __shared__ float    hrL[ROWS * 64];         // 1 KB epilogue row tile
  __shared__ unsigned LwMin[ROWS][ROWS], LwMax[ROWS][ROWS];
  __shared__ int   seli[ROWS][52];
  __shared__ float selv[ROWS][52];
  __shared__ int   eqlist[ROWS][56];

  const float* hb  = h  + (size_t)b * N_NODES * 64;
  const float* hTb = hT + (size_t)b * 64 * N_NODES;
  const float* colp = hTb + 4 * tid;      // group A: cols 4*tid..+3; B at +1024

  // prefetch ring depth 4 per group (issued before anything else)
  float4 pfA[4], pfB[4];
#pragma unroll
  for (int i = 0; i < 4; ++i) {
    pfA[i] = *(const float4*)(colp + (size_t)i * 2048);
    pfB[i] = *(const float4*)(colp + (size_t)i * 2048 + 1024);
  }

  if (!FINAL) hrL[tid] = hb[(size_t)n0 * 64 + tid];    // ROWS*64 == 256
  for (int i = tid; i < ROWS * 256; i += 256) (&hist[0][0])[i] = 0;

  // ---- FMA phase: acc2[r*4+q]: q=0,1 -> group A pairs; q=2,3 -> group B pairs
  v2f acc2[16];
#pragma unroll
  for (int i = 0; i < 16; ++i) { acc2[i][0] = 0.f; acc2[i][1] = 0.f; }

  const float* hrow = hb + (size_t)n0 * 64;            // block-uniform -> SGPR
  float4 a_cur[ROWS], a_nxt[ROWS];
#pragma unroll
  for (int r = 0; r < ROWS; ++r)
    a_cur[r] = *(const float4*)(hrow + r * 64);
  for (int k4 = 0; k4 < 16; ++k4) {
    if (k4 + 1 < 16) {                                 // prefetch next k4's rows
#pragma unroll
      for (int r = 0; r < ROWS; ++r)
        a_nxt[r] = *(const float4*)(hrow + r * 64 + (k4 + 1) * 4);
    }
#pragma unroll
    for (int kk = 0; kk < 4; ++kk) {
      const int k = k4 * 4 + kk;
      float4 cA = pfA[kk], cB = pfB[kk];               // ring: kk == k&3
      if (k + 4 < 64) {
        pfA[kk] = *(const float4*)(colp + (size_t)(k + 4) * 2048);
        pfB[kk] = *(const float4*)(colp + (size_t)(k + 4) * 2048 + 1024);
      }
      v2f cA0 = {cA.x, cA.y}, cA1 = {cA.z, cA.w};
      v2f cB0 = {cB.x, cB.y}, cB1 = {cB.z, cB.w};
#pragma unroll
      for (int r = 0; r < ROWS; ++r) {
        const float ar = ((const float*)&a_cur[r])[kk];
        v2f as = {ar, ar};
        acc2[r*4+0] = __builtin_elementwise_fma(as, cA0, acc2[r*4+0]);
        acc2[r*4+1] = __builtin_elementwise_fma(as, cA1, acc2[r*4+1]);
        acc2[r*4+2] = __builtin_elementwise_fma(as, cB0, acc2[r*4+2]);
        acc2[r*4+3] = __builtin_elementwise_fma(as, cB1, acc2[r*4+3]);
      }
    }
#pragma unroll
    for (int r = 0; r < ROWS; ++r) a_cur[r] = a_nxt[r];
  }

  // ---- convert, park in LDS, reg-based prefilter reductions
#pragma unroll
  for (int r = 0; r < ROWS; ++r) {
    uint4 wA, wB;
    wA.x = ford(acc2[r*4+0][0]); wA.y = ford(acc2[r*4+0][1]);
    wA.z = ford(acc2[r*4+1][0]); wA.w = ford(acc2[r*4+1][1]);
    wB.x = ford(acc2[r*4+2][0]); wB.y = ford(acc2[r*4+2][1]);
    wB.z = ford(acc2[r*4+3][0]); wB.w = ford(acc2[r*4+3][1]);
    *(uint4*)&Sbuf[r * N_NODES + 4 * tid] = wA;
    *(uint4*)&Sbuf[r * N_NODES + 1024 + 4 * tid] = wB;
    unsigned mA1 = wA.x > wA.y ? wA.x : wA.y, mA2 = wA.z > wA.w ? wA.z : wA.w;
    unsigned mB1 = wB.x > wB.y ? wB.x : wB.y, mB2 = wB.z > wB.w ? wB.z : wB.w;
    unsigned mA = mA1 > mA2 ? mA1 : mA2, mB = mB1 > mB2 ? mB1 : mB2;
    unsigned lm = mA > mB ? mA : mB;           // per-lane max of its 8 vals
    unsigned mn = lm, mx = lm;
#pragma unroll
    for (int off = 32; off >= 1; off >>= 1) {
      unsigned o1 = (unsigned)__shfl_xor((int)mn, off, 64);
      unsigned o2 = (unsigned)__shfl_xor((int)mx, off, 64);
      mn = mn < o1 ? mn : o1;                  // wave-min of lane maxes
      mx = mx > o2 ? mx : o2;                  // wave-max
    }
    if (lane == 0) { LwMin[w64][r] = mn; LwMax[w64][r] = mx; }
  }
  __syncthreads();                             // barrier 1: Sbuf/LwMM/hrL ready

  // ======== wave-private selection: wave w64 owns row rw ========
  const int rw = w64;
  const unsigned* Srow = &Sbuf[rw * N_NODES];
  unsigned Lv, Tv;
  {
    unsigned lmn = (lane < ROWS) ? LwMin[lane][rw] : 0u;
    unsigned lmx = (lane < ROWS) ? LwMax[lane][rw] : 0u;
#pragma unroll
    for (int off = 2; off >= 1; off >>= 1) {
      unsigned o1 = (unsigned)__shfl_xor((int)lmn, off, 4);
      unsigned o2 = (unsigned)__shfl_xor((int)lmx, off, 4);
      lmn = lmn > o1 ? lmn : o1;               // L = max over waves of wave-mins
      lmx = lmx > o2 ? lmx : o2;               // M = row max
    }
    Lv = (unsigned)__shfl((int)lmn, 0, 64);
    unsigned Mv = (unsigned)__shfl((int)lmx, 0, 64);

    if (Lv == Mv) {
      Tv = Mv;                                 // >=64 copies of the max
    } else {
      int sh = 24 - 8 * (__builtin_clz(Lv ^ Mv) >> 3);
      unsigned pv = (unsigned)(((unsigned long long)Lv) >> (sh + 8));
      unsigned Kc = KSEL;
      int mode = 0;                            // 0=HIST 1=PROBE 2=DONE
      unsigned* hrw = hist[rw];
      for (int it = 0; it < 5 && mode != 2; ++it) {
        // wave-uniform candidate range: prefix pv at bits [31 : sh+8]
        // <=> lo2 <= v <= hi  (two compares/value, hoist-proof)
        const int s2 = sh + 8;                 // 8..32
        const unsigned lo = (s2 >= 32) ? 0u : (pv << s2);
        const unsigned hi = (s2 >= 32) ? 0xFFFFFFFFu : (lo | ((1u << s2) - 1u));
        const unsigned lo2 = lo > Lv ? lo : Lv;
        if (mode == 0) {
#pragma unroll
          for (int i = 0; i < 8; ++i) {
            uint4 q = *(const uint4*)&Srow[i * 256 + 4 * lane];
            unsigned vv[4] = {q.x, q.y, q.z, q.w};
#pragma unroll
            for (int e = 0; e < 4; ++e) {
              unsigned v = vv[e];
              if (v >= lo2 && v <= hi)
                atomicAdd(&hrw[hidx1((v >> sh) & 255u)], 1u);
            }
          }
          uint4 q = *(const uint4*)&hrw[lane * 4];
          *(uint4*)&hrw[lane * 4] = make_uint4(0, 0, 0, 0);
          unsigned c0 = q.x, c1 = q.y, c2 = q.z, c3 = q.w;
          unsigned s0 = c0, s1 = c1, s2s = c2, s3 = c3;  // suffix over lanes
#pragma unroll
          for (int off = 1; off < 64; off <<= 1) {
            unsigned t0=__shfl_down((int)s0,off,64), t1=__shfl_down((int)s1,off,64);
            unsigned t2=__shfl_down((int)s2s,off,64), t3=__shfl_down((int)s3,off,64);
            if (lane + off < 64) { s0+=t0; s1+=t1; s2s+=t2; s3+=t3; }
          }
          unsigned T1=(unsigned)__shfl((int)s1,0,64);
          unsigned T2=(unsigned)__shfl((int)s2s,0,64);
          unsigned T3=(unsigned)__shfl((int)s3,0,64);
          unsigned cA4[4] = {c0, c1, c2, c3};
          unsigned AA[4] = {s0 - c0 + T1 + T2 + T3, s1 - c1 + T2 + T3,
                            s2s - c2 + T3,          s3 - c3};
          int fg = -1;
#pragma unroll
          for (int g = 0; g < 4; ++g)
            if (AA[g] < Kc && Kc <= AA[g] + cA4[g]) fg = g;
          unsigned long long mk = __ballot(fg >= 0);
          int src = __ffsll(mk) - 1;           // exactly one lane fires
          unsigned bin = 0, nKc = 0, cnt = 0;
          if (fg >= 0) {
            bin = (unsigned)(fg * 64 + lane);
            nKc = Kc - AA[fg];
            cnt = cA4[fg];
          }
          bin = (unsigned)__shfl((int)bin, src, 64);
          nKc = (unsigned)__shfl((int)nKc, src, 64);
          cnt = (unsigned)__shfl((int)cnt, src, 64);
          pv = (pv << 8) | bin;
          Kc = nKc;
          sh -= 8;
          if (sh < 0)        { Tv = pv; mode = 2; }
          else if (cnt == 1) mode = 1;
        } else {
          // PROBE: the unique candidate in [lo2,hi] is T
          unsigned found = 0; bool has = false;
#pragma unroll
          for (int i = 0; i < 8; ++i) {
            uint4 q = *(const uint4*)&Srow[i * 256 + 4 * lane];
            unsigned vv[4] = {q.x, q.y, q.z, q.w};
#pragma unroll
            for (int e = 0; e < 4; ++e) {
              unsigned v = vv[e];
              if (v >= lo2 && v <= hi) { found = v; has = true; }
            }
          }
          unsigned long long mk = __ballot(has);
          int src = __ffsll(mk) - 1;
          Tv = (unsigned)__shfl((int)found, src, 64);
          mode = 2;
        }
      }
    }
  }

  // ---- extraction: load row once (select state dead), counts + prefix scans
  unsigned vals[32];
  int cgt = 0, ceq = 0;
#pragma unroll
  for (int i = 0; i < 8; ++i) {
    uint4 q = *(const uint4*)&Srow[i * 256 + 4 * lane];
    vals[i*4+0] = q.x; vals[i*4+1] = q.y; vals[i*4+2] = q.z; vals[i*4+3] = q.w;
#pragma unroll
    for (int e = 0; e < 4; ++e) {
      cgt += (vals[i*4+e] > Tv);
      ceq += (vals[i*4+e] == Tv);
    }
  }
  int sg = cgt, se = ceq;
#pragma unroll
  for (int off = 1; off < 64; off <<= 1) {
    int t0 = __shfl_up(sg, off, 64), t1 = __shfl_up(se, off, 64);
    if (lane >= off) { sg += t0; se += t1; }
  }
  const int gW = __shfl(sg, 63, 64);           // total winners (> T), < 50
  const int eTot = __shfl(se, 63, 64);
  int gb = sg - cgt, eb = se - ceq;            // exclusive bases

  float* ob = FINAL ? (outp + ((size_t)b * N_NODES + n0 + rw) * N_NODES) : nullptr;
  if constexpr (FINAL) {
    // masked dense write fused with extraction; ties fixed up after resolve
#pragma unroll
    for (int i = 0; i < 8; ++i) {
      float4 w; float* wf = (float*)&w;
#pragma unroll
      for (int e = 0; e < 4; ++e) {
        unsigned v = vals[i*4+e];
        wf[e] = (v > Tv) ? funord(v) : 0.f;
        if (v == Tv) { if (eb < 56) eqlist[rw][eb] = i * 256 + 4 * lane + e; ++eb; }
      }
      *(float4*)(ob + i * 256 + 4 * lane) = w;
    }
  } else {
#pragma unroll
    for (int i = 0; i < 8; ++i) {
#pragma unroll
      for (int e = 0; e < 4; ++e) {
        unsigned v = vals[i*4+e];
        int m = i * 256 + 4 * lane + e;
        if (v > Tv) { seli[rw][gb] = m; selv[rw][gb] = funord(v); ++gb; }
        else if (v == Tv) { if (eb < 56) eqlist[rw][eb] = m; ++eb; }
      }
    }
  }
  const int eW = eTot < 56 ? eTot : 56;

  // ---- tie-resolve, wave-parallel: `need` smallest indices among equals
  const int needW = KSEL - gW;
  const float Tf = funord(Tv);
  {
    int myi = (lane < eW) ? eqlist[rw][lane] : 0x7FFFFFFF;
    for (int t = 0; t < needW; ++t) {
      int mn = myi;
#pragma unroll
      for (int off = 32; off >= 1; off >>= 1) {
        int o = __shfl_xor(mn, off, 64);
        mn = mn < o ? mn : o;
      }
      if (mn == 0x7FFFFFFF) break;
      if (myi == mn) {
        if (!FINAL) { seli[rw][gW + t] = mn; selv[rw][gW + t] = Tf; }
        else eqlist[rw][t] = mn;               // reuse as fixup list
        myi = 0x7FFFFFFF;
      }
    }
  }

  if constexpr (FINAL) {
    if (lane < needW) ob[eqlist[rw][lane]] = Tf;         // tie fixups
  } else {
    // aggregation into per-row Sbuf overlay (wave-private region; row is dead)
    // batched gather: groups of 10 independent L2 loads in flight
    float* aggbR = (float*)&Sbuf[rw * N_NODES + 1024];
    {
      const float* msgb = msg + (size_t)b * N_NODES * 64;
      float a0 = 0.f, a1 = 0.f;
#pragma unroll
      for (int i0 = 0; i0 < KSEL; i0 += 10) {
        int mi[10]; float vv[10], mv[10];
#pragma unroll
        for (int j = 0; j < 10; ++j) {
          mi[j] = seli[rw][i0 + j];            // wave-uniform LDS broadcast
          vv[j] = selv[rw][i0 + j];
        }
#pragma unroll
        for (int j = 0; j < 10; ++j)
          mv[j] = msgb[(size_t)mi[j] * 64 + lane];
#pragma unroll
        for (int j = 0; j < 10; ++j) {
          if (j & 1) a1 += vv[j] * mv[j];
          else       a0 += vv[j] * mv[j];
        }
      }
      aggbR[lane] = a0 + a1;
    }
    // update MLP: h2[rw][lane]; dual chains break the serial FMA dependency
    float s0 = bu[lane], s1 = 0.f;
#pragma unroll 8
    for (int jj = 0; jj < 64; jj += 2) {
      s0 += hrL[rw * 64 + jj]     * wu[jj * 64 + lane];
      s1 += hrL[rw * 64 + jj + 1] * wu[(jj + 1) * 64 + lane];
    }
#pragma unroll 8
    for (int jj = 0; jj < 64; jj += 2) {
      s0 += aggbR[jj]     * wu[(64 + jj) * 64 + lane];
      s1 += aggbR[jj + 1] * wu[(64 + jj + 1) * 64 + lane];
    }
    float s = fmaxf(s0 + s1, 0.f);
    outp[((size_t)b * N_NODES + n0 + rw) * 64 + lane] = s;
    __syncthreads();                           // all waves done with Sbuf
    float* otF = (float*)Sbuf;                 // transpose staging overlay
    otF[lane * 9 + rw] = s;                    // stride 9: conflict-free
    __syncthreads();
    {                                          // flush h2T: 64 feats x 4 rows
      int f = tid >> 2, rr = tid & 3;
      outT[(size_t)b * 64 * N_NODES + (size_t)f * N_NODES + n0 + rr] = otF[f * 9 + rr];
    }
  }
}

extern "C" void kernel_launch(void* const* d_in, const int* in_sizes, int n_in,
                              void* d_out, int out_size, void* d_ws, size_t ws_size,
                              hipStream_t stream)
{
  (void)in_sizes; (void)n_in; (void)out_size; (void)ws_size;
  const float* x   = (const float*)d_in[0];
  const float* ew0 = (const float*)d_in[1];
  const float* eb0 = (const float*)d_in[2];
  const float* ew1 = (const float*)d_in[3];
  const float* eb1 = (const float*)d_in[4];
  const float* w0m = (const float*)d_in[5];
  const float* b0m = (const float*)d_in[6];
  const float* w0u = (const float*)d_in[7];
  const float* b0u = (const float*)d_in[8];
  const float* w1m = (const float*)d_in[9];
  const float* b1m = (const float*)d_in[10];
  const float* w1u = (const float*)d_in[11];
  const float* b1u = (const float*)d_in[12];
  float* out = (float*)d_out;
  float* ws = (float*)d_ws;

  const size_t BUF = (size_t)8 * N_NODES * 64;  // 4 MB each, 20 MB total ws
  float* A   = ws;
  float* AT  = ws + 1 * BUF;
  float* Bf  = ws + 2 * BUF;
  float* BfT = ws + 3 * BUF;
  float* C   = ws + 4 * BUF;

  const int NBLK = 8 * (N_NODES / ROWS);        // 4096

  // fused embedding (2 layers) + msg0
  emb3_kernel<<<256, 256, 0, stream>>>(x, ew0, eb0, ew1, eb1, w0m, b0m, A, AT, C);

  // MP layer 0 (consumes msg0=C, produces Bf/BfT)
  mp_kernel<false><<<NBLK, 256, 0, stream>>>(A, AT, C, w0u, b0u, Bf, BfT);

  // msg1
  linrelu_kernel<<<256, 256, 0, stream>>>(Bf, w1m, b1m, C);

  // MP layer 1
  mp_kernel<false><<<NBLK, 256, 0, stream>>>(Bf, BfT, C, w1u, b1u, A, AT);

  // final dense top-k adjacency
  mp_kernel<true><<<NBLK, 256, 0, stream>>>(A, AT, nullptr, nullptr, nullptr, out, nullptr);
}